// Round 1
// baseline (163.386 us; speedup 1.0000x reference)
//
#include <hip/hip_runtime.h>
#include <math.h>

#define BATCH 16
#define NUM_HEADS 16
#define HEAD_DIM 64
#define HIDDEN 1024
#define BLOCK_SIZE 16
#define MAX_CTX 4096
#define BLOCKS_PER_SEQ 256
#define SPLITS 8
#define SPLIT_TOK 512  // MAX_CTX / SPLITS

// workspace layout in floats
#define Q_OFF   0
#define K_OFF   16384
#define V_OFF   32768
#define AO_OFF  49152
#define PML_OFF 65536              // BATCH*NUM_HEADS*SPLITS*2 = 4096
#define PO_OFF  69632              // BATCH*NUM_HEADS*SPLITS*64 = 131072
// total 200704 floats = 802816 bytes

// GEMV: out[m][b][row] = sum_i X[b][i] * W_m[row][i]
// grid.x * 16 rows total; rows 0..1023 -> W0/out0, 1024..2047 -> W1/out1, 2048..3071 -> W2/out2
__global__ void proj_kernel(const float* __restrict__ X,
                            const float* __restrict__ W0,
                            const float* __restrict__ W1,
                            const float* __restrict__ W2,
                            float* __restrict__ out0,
                            float* __restrict__ out1,
                            float* __restrict__ out2) {
    const int tid = threadIdx.x;
    const int b = tid & 15;
    const int r = tid >> 4;                  // 0..15
    const int row = blockIdx.x * 16 + r;
    const int m = row >> 10;
    const int row_in = row & 1023;
    const float* W = (m == 0) ? W0 : (m == 1) ? W1 : W2;
    float* out = (m == 0) ? out0 : (m == 1) ? out1 : out2;

    const float4* wrow = (const float4*)(W + (size_t)row_in * HIDDEN);
    const float4* xrow = (const float4*)(X + (size_t)b * HIDDEN);
    float acc = 0.f;
#pragma unroll 8
    for (int i = 0; i < HIDDEN / 4; ++i) {
        float4 w4 = wrow[i];
        float4 x4 = xrow[i];
        acc += w4.x * x4.x + w4.y * x4.y + w4.z * x4.z + w4.w * x4.w;
    }
    out[(size_t)b * HIDDEN + row_in] = acc;
}

// Flash-decode partial: grid (SPLITS, NUM_HEADS, BATCH), 256 threads.
// Scans cache tokens [t0, min(t0+SPLIT_TOK, pos)) -- strictly BELOW pos; the
// token at pos (the new k/v) is handled in attn_reduce.
__global__ void attn_partial(const float* __restrict__ q_ws,
                             const float* __restrict__ key_cache,
                             const float* __restrict__ value_cache,
                             const int* __restrict__ block_table,
                             const int* __restrict__ positions,
                             float* __restrict__ part_ml,
                             float* __restrict__ part_o) {
    const int s = blockIdx.x;
    const int h = blockIdx.y;
    const int b = blockIdx.z;
    const int tid = threadIdx.x;          // 0..255
    const int lane = tid & 63;
    const int w = tid >> 6;               // wave 0..3
    const int g = lane >> 4;              // group-in-wave 0..3
    const int sub = lane & 15;            // 0..15
    const int gid = w * 4 + g;            // 0..15

    __shared__ int bt_lds[SPLIT_TOK / BLOCK_SIZE];   // 32
    __shared__ float gm[16];
    __shared__ float gl[16];
    __shared__ float go[16][64];

    const int pos = positions[b];
    const int t0 = s * SPLIT_TOK;
    const int t1 = min(t0 + SPLIT_TOK, pos);

    if (tid < SPLIT_TOK / BLOCK_SIZE) {
        bt_lds[tid] = block_table[b * BLOCKS_PER_SEQ + t0 / BLOCK_SIZE + tid];
    }
    __syncthreads();

    const float4 q4 = ((const float4*)(q_ws + (size_t)b * HIDDEN + h * HEAD_DIM))[sub];

    float m = -1e30f;
    float l = 0.f;
    float4 o4 = {0.f, 0.f, 0.f, 0.f};

    for (int t = t0 + w * 4 + g; t < t1; t += 16) {
        const int blk = bt_lds[(t - t0) >> 4];
        const int slot = t & 15;
        const size_t base = (((size_t)blk * BLOCK_SIZE + slot) * NUM_HEADS + h) * HEAD_DIM;
        const float4 k4 = ((const float4*)(key_cache + base))[sub];
        const float4 v4 = ((const float4*)(value_cache + base))[sub];
        float d = k4.x * q4.x + k4.y * q4.y + k4.z * q4.z + k4.w * q4.w;
        d += __shfl_xor(d, 1);
        d += __shfl_xor(d, 2);
        d += __shfl_xor(d, 4);
        d += __shfl_xor(d, 8);
        const float sc = d * 0.125f;   // 1/sqrt(64)
        const float m_new = fmaxf(m, sc);
        const float corr = __expf(m - m_new);
        const float p = __expf(sc - m_new);
        l = l * corr + p;
        o4.x = o4.x * corr + p * v4.x;
        o4.y = o4.y * corr + p * v4.y;
        o4.z = o4.z * corr + p * v4.z;
        o4.w = o4.w * corr + p * v4.w;
        m = m_new;
    }

    go[gid][sub * 4 + 0] = o4.x;
    go[gid][sub * 4 + 1] = o4.y;
    go[gid][sub * 4 + 2] = o4.z;
    go[gid][sub * 4 + 3] = o4.w;
    if (sub == 0) { gm[gid] = m; gl[gid] = l; }
    __syncthreads();

    if (tid < 64) {
        const int d = tid;
        float M = -1e30f;
#pragma unroll
        for (int gi = 0; gi < 16; ++gi) M = fmaxf(M, gm[gi]);
        float L = 0.f, O = 0.f;
#pragma unroll
        for (int gi = 0; gi < 16; ++gi) {
            const float sc = __expf(gm[gi] - M);
            L += gl[gi] * sc;
            O += go[gi][d] * sc;
        }
        const int pidx = (b * NUM_HEADS + h) * SPLITS + s;
        part_o[(size_t)pidx * 64 + d] = O;
        if (d == 0) {
            part_ml[pidx * 2 + 0] = M;
            part_ml[pidx * 2 + 1] = L;
        }
    }
}

// Merge split partials + the new-token (tok == pos) term. grid = B*H, 64 thr.
__global__ void attn_reduce(const float* __restrict__ q_ws,
                            const float* __restrict__ k_ws,
                            const float* __restrict__ v_ws,
                            const float* __restrict__ part_ml,
                            const float* __restrict__ part_o,
                            float* __restrict__ attn_out) {
    const int bh = blockIdx.x;          // b*16 + h
    const int b = bh >> 4;
    const int h = bh & 15;
    const int d = threadIdx.x;          // 0..63

    const size_t vecoff = (size_t)b * HIDDEN + h * HEAD_DIM + d;
    const float qd = q_ws[vecoff];
    const float kd = k_ws[vecoff];
    float pr = qd * kd;
    pr += __shfl_xor(pr, 1);
    pr += __shfl_xor(pr, 2);
    pr += __shfl_xor(pr, 4);
    pr += __shfl_xor(pr, 8);
    pr += __shfl_xor(pr, 16);
    pr += __shfl_xor(pr, 32);
    const float s_new = pr * 0.125f;

    float M = s_new;
#pragma unroll
    for (int sp = 0; sp < SPLITS; ++sp)
        M = fmaxf(M, part_ml[(bh * SPLITS + sp) * 2]);

    float L = __expf(s_new - M);
    float O = L * v_ws[vecoff];
#pragma unroll
    for (int sp = 0; sp < SPLITS; ++sp) {
        const float mg = part_ml[(bh * SPLITS + sp) * 2 + 0];
        const float lg = part_ml[(bh * SPLITS + sp) * 2 + 1];
        const float sc = __expf(mg - M);
        L += lg * sc;
        O += part_o[(size_t)(bh * SPLITS + sp) * 64 + d] * sc;
    }
    attn_out[vecoff] = O / L;
}

extern "C" void kernel_launch(void* const* d_in, const int* in_sizes, int n_in,
                              void* d_out, int out_size, void* d_ws, size_t ws_size,
                              hipStream_t stream) {
    const float* hidden      = (const float*)d_in[0];
    const float* key_cache   = (const float*)d_in[1];
    const float* value_cache = (const float*)d_in[2];
    const int*   block_table = (const int*)d_in[3];
    const int*   positions   = (const int*)d_in[4];
    const float* Wq          = (const float*)d_in[5];
    const float* Wk          = (const float*)d_in[6];
    const float* Wv          = (const float*)d_in[7];
    const float* Wo          = (const float*)d_in[8];
    float* out = (float*)d_out;

    float* ws = (float*)d_ws;
    float* q_ws  = ws + Q_OFF;
    float* k_ws  = ws + K_OFF;
    float* v_ws  = ws + V_OFF;
    float* ao_ws = ws + AO_OFF;
    float* pml   = ws + PML_OFF;
    float* po    = ws + PO_OFF;

    // 1) q/k/v projections: 3*1024 rows, 16 rows per block
    proj_kernel<<<192, 256, 0, stream>>>(hidden, Wq, Wk, Wv, q_ws, k_ws, v_ws);

    // 2) flash-decode partials over the (unmodified) caches
    attn_partial<<<dim3(SPLITS, NUM_HEADS, BATCH), 256, 0, stream>>>(
        q_ws, key_cache, value_cache, block_table, positions, pml, po);

    // 3) merge splits + new-token contribution
    attn_reduce<<<BATCH * NUM_HEADS, 64, 0, stream>>>(q_ws, k_ws, v_ws, pml, po, ao_ws);

    // 4) output projection: 1024 rows
    proj_kernel<<<64, 256, 0, stream>>>(ao_ws, Wo, Wo, Wo, out, out, out);
}

// Round 2
// 118.830 us; speedup vs baseline: 1.3750x; 1.3750x over previous
//
#include <hip/hip_runtime.h>
#include <math.h>

#define BATCH 16
#define NUM_HEADS 16
#define HEAD_DIM 64
#define HIDDEN 1024
#define BLOCK_SIZE 16
#define MAX_CTX 4096
#define BLOCKS_PER_SEQ 256
#define SPLITS 8
#define SPLIT_TOK 512  // MAX_CTX / SPLITS
#define CHUNKS 4
#define CHUNK_F4 64    // (HIDDEN/CHUNKS)/4

// workspace layout in floats
#define Q_OFF   0
#define K_OFF   16384
#define V_OFF   32768
#define AO_OFF  49152
#define PML_OFF 65536              // BATCH*NUM_HEADS*SPLITS*2 = 4096
#define PO_OFF  69632              // BATCH*NUM_HEADS*SPLITS*64 = 131072
#define PART_OFF 200704            // CHUNKS*3072*16 = 196608
// total ~397312 floats = 1.6 MB

#define LOG2E 1.4426950408889634f

// Split-K GEMV partial: rows 0..1023 -> W0, 1024..2047 -> W1, 2048..3071 -> W2.
// grid = (row_groups, CHUNKS). Each thread: one (row, batch) pair, 1/4 of the dot.
__global__ void proj_partial(const float* __restrict__ X,
                             const float* __restrict__ W0,
                             const float* __restrict__ W1,
                             const float* __restrict__ W2,
                             float* __restrict__ part, int NR) {
    const int tid = threadIdx.x;
    const int b = tid & 15;
    const int r = tid >> 4;                  // 0..15
    const int row = blockIdx.x * 16 + r;
    const int c = blockIdx.y;
    const int m = row >> 10;
    const int row_in = row & 1023;
    const float* W = (m == 0) ? W0 : (m == 1) ? W1 : W2;

    const float4* wrow = (const float4*)(W + (size_t)row_in * HIDDEN) + c * CHUNK_F4;
    const float4* xrow = (const float4*)(X + (size_t)b * HIDDEN) + c * CHUNK_F4;
    float acc = 0.f;
#pragma unroll 16
    for (int i = 0; i < CHUNK_F4; ++i) {
        float4 w4 = wrow[i];
        float4 x4 = xrow[i];
        acc += w4.x * x4.x + w4.y * x4.y + w4.z * x4.z + w4.w * x4.w;
    }
    part[((size_t)c * NR + row) * 16 + b] = acc;
}

__global__ void proj_combine(const float* __restrict__ part,
                             float* __restrict__ out0,
                             float* __restrict__ out1,
                             float* __restrict__ out2, int NR) {
    const int idx = blockIdx.x * 256 + threadIdx.x;  // row*16 + b
    const int row = idx >> 4;
    const int b = idx & 15;
    float s = 0.f;
#pragma unroll
    for (int c = 0; c < CHUNKS; ++c) s += part[((size_t)c * NR + row) * 16 + b];
    const int m = row >> 10;
    const int row_in = row & 1023;
    float* out = (m == 0) ? out0 : (m == 1) ? out1 : out2;
    out[(size_t)b * HIDDEN + row_in] = s;
}

// Flash-decode partial: grid (SPLITS, NUM_HEADS, BATCH), 256 threads.
// Each 16-lane group handles 4 tokens per iteration (64 tokens per block-iter).
// Softmax tracked in log2 domain; scale*log2e folded into q.
// Scans tokens strictly < pos; token at pos handled in attn_reduce.
__global__ void attn_partial(const float* __restrict__ q_ws,
                             const float* __restrict__ key_cache,
                             const float* __restrict__ value_cache,
                             const int* __restrict__ block_table,
                             const int* __restrict__ positions,
                             float* __restrict__ part_ml,
                             float* __restrict__ part_o) {
    const int s = blockIdx.x;
    const int h = blockIdx.y;
    const int b = blockIdx.z;
    const int tid = threadIdx.x;          // 0..255
    const int lane = tid & 63;
    const int w = tid >> 6;               // wave 0..3
    const int g = lane >> 4;              // group-in-wave 0..3
    const int sub = lane & 15;            // 0..15
    const int gid = w * 4 + g;            // 0..15

    __shared__ int bt_lds[SPLIT_TOK / BLOCK_SIZE];   // 32
    __shared__ float gm[16];
    __shared__ float gl[16];
    __shared__ float go[16][64];

    const int pos = positions[b];
    const int t0 = s * SPLIT_TOK;
    const int t1 = min(t0 + SPLIT_TOK, pos);
    const int nvalid = t1 - t0;

    if (tid < SPLIT_TOK / BLOCK_SIZE) {
        bt_lds[tid] = block_table[b * BLOCKS_PER_SEQ + (t0 >> 4) + tid];
    }
    __syncthreads();

    float4 q4 = ((const float4*)(q_ws + (size_t)b * HIDDEN + h * HEAD_DIM))[sub];
    const float qs = 0.125f * LOG2E;   // 1/sqrt(64) * log2(e)
    q4.x *= qs; q4.y *= qs; q4.z *= qs; q4.w *= qs;

    float m = -1e30f;
    float l = 0.f;
    float4 o4 = {0.f, 0.f, 0.f, 0.f};

    // iteration covers tokens [t0 + it*64, t0 + it*64 + 64); wave w owns one
    // 16-token page (bt_lds[it*4+w]); group g owns slots {g, g+4, g+8, g+12}... no:
    // slot_j = j*4 + g  (j = 0..3), so wave's 4 groups per j are consecutive slots.
    for (int it = 0; it * 64 < nvalid; ++it) {
        const int blk = bt_lds[it * 4 + w];   // wave-uniform
        const float* kp = key_cache + ((size_t)blk * BLOCK_SIZE + g) * (NUM_HEADS * HEAD_DIM)
                          + h * HEAD_DIM + sub * 4;
        const float* vp = value_cache + ((size_t)blk * BLOCK_SIZE + g) * (NUM_HEADS * HEAD_DIM)
                          + h * HEAD_DIM + sub * 4;
        // 8 independent 16B loads in flight
        const float4 k0 = *(const float4*)(kp);
        const float4 k1 = *(const float4*)(kp + 4 * 1024);
        const float4 k2 = *(const float4*)(kp + 8 * 1024);
        const float4 k3 = *(const float4*)(kp + 12 * 1024);
        const float4 v0 = *(const float4*)(vp);
        const float4 v1 = *(const float4*)(vp + 4 * 1024);
        const float4 v2 = *(const float4*)(vp + 8 * 1024);
        const float4 v3 = *(const float4*)(vp + 12 * 1024);

        float d0 = k0.x * q4.x + k0.y * q4.y + k0.z * q4.z + k0.w * q4.w;
        float d1 = k1.x * q4.x + k1.y * q4.y + k1.z * q4.z + k1.w * q4.w;
        float d2 = k2.x * q4.x + k2.y * q4.y + k2.z * q4.z + k2.w * q4.w;
        float d3 = k3.x * q4.x + k3.y * q4.y + k3.z * q4.z + k3.w * q4.w;
#pragma unroll
        for (int mask = 1; mask <= 8; mask <<= 1) {
            d0 += __shfl_xor(d0, mask);
            d1 += __shfl_xor(d1, mask);
            d2 += __shfl_xor(d2, mask);
            d3 += __shfl_xor(d3, mask);
        }
        // token of slice j: t0 + it*64 + w*16 + j*4 + g
        const int tb = t0 + it * 64 + w * 16 + g;
        if (tb + 0  >= t1) d0 = -INFINITY;
        if (tb + 4  >= t1) d1 = -INFINITY;
        if (tb + 8  >= t1) d2 = -INFINITY;
        if (tb + 12 >= t1) d3 = -INFINITY;

        const float mx = fmaxf(fmaxf(d0, d1), fmaxf(d2, d3));
        const float m_new = fmaxf(m, mx);
        const float corr = exp2f(m - m_new);
        const float p0 = exp2f(d0 - m_new);
        const float p1 = exp2f(d1 - m_new);
        const float p2 = exp2f(d2 - m_new);
        const float p3 = exp2f(d3 - m_new);
        l = l * corr + ((p0 + p1) + (p2 + p3));
        o4.x = o4.x * corr + p0 * v0.x + p1 * v1.x + p2 * v2.x + p3 * v3.x;
        o4.y = o4.y * corr + p0 * v0.y + p1 * v1.y + p2 * v2.y + p3 * v3.y;
        o4.z = o4.z * corr + p0 * v0.z + p1 * v1.z + p2 * v2.z + p3 * v3.z;
        o4.w = o4.w * corr + p0 * v0.w + p1 * v1.w + p2 * v2.w + p3 * v3.w;
        m = m_new;
    }

    go[gid][sub * 4 + 0] = o4.x;
    go[gid][sub * 4 + 1] = o4.y;
    go[gid][sub * 4 + 2] = o4.z;
    go[gid][sub * 4 + 3] = o4.w;
    if (sub == 0) { gm[gid] = m; gl[gid] = l; }
    __syncthreads();

    if (tid < 64) {
        const int d = tid;
        float M = -1e30f;
#pragma unroll
        for (int gi = 0; gi < 16; ++gi) M = fmaxf(M, gm[gi]);
        float L = 0.f, O = 0.f;
#pragma unroll
        for (int gi = 0; gi < 16; ++gi) {
            const float sc = exp2f(gm[gi] - M);   // log2-domain maxes
            L += gl[gi] * sc;
            O += go[gi][d] * sc;
        }
        const int pidx = (b * NUM_HEADS + h) * SPLITS + s;
        part_o[(size_t)pidx * 64 + d] = O;
        if (d == 0) {
            part_ml[pidx * 2 + 0] = M;   // log2 domain
            part_ml[pidx * 2 + 1] = L;
        }
    }
}

// Merge split partials + the new-token (tok == pos) term. grid = B*H, 64 thr.
__global__ void attn_reduce(const float* __restrict__ q_ws,
                            const float* __restrict__ k_ws,
                            const float* __restrict__ v_ws,
                            const float* __restrict__ part_ml,
                            const float* __restrict__ part_o,
                            float* __restrict__ attn_out) {
    const int bh = blockIdx.x;          // b*16 + h
    const int b = bh >> 4;
    const int h = bh & 15;
    const int d = threadIdx.x;          // 0..63

    const size_t vecoff = (size_t)b * HIDDEN + h * HEAD_DIM + d;
    const float qd = q_ws[vecoff];
    const float kd = k_ws[vecoff];
    float pr = qd * kd;
    pr += __shfl_xor(pr, 1);
    pr += __shfl_xor(pr, 2);
    pr += __shfl_xor(pr, 4);
    pr += __shfl_xor(pr, 8);
    pr += __shfl_xor(pr, 16);
    pr += __shfl_xor(pr, 32);
    const float s_new = pr * (0.125f * LOG2E);   // log2 domain

    float M = s_new;
#pragma unroll
    for (int sp = 0; sp < SPLITS; ++sp)
        M = fmaxf(M, part_ml[(bh * SPLITS + sp) * 2]);

    float L = exp2f(s_new - M);
    float O = L * v_ws[vecoff];
#pragma unroll
    for (int sp = 0; sp < SPLITS; ++sp) {
        const float mg = part_ml[(bh * SPLITS + sp) * 2 + 0];
        const float lg = part_ml[(bh * SPLITS + sp) * 2 + 1];
        const float sc = exp2f(mg - M);
        L += lg * sc;
        O += part_o[(size_t)(bh * SPLITS + sp) * 64 + d] * sc;
    }
    attn_out[vecoff] = O / L;
}

extern "C" void kernel_launch(void* const* d_in, const int* in_sizes, int n_in,
                              void* d_out, int out_size, void* d_ws, size_t ws_size,
                              hipStream_t stream) {
    const float* hidden      = (const float*)d_in[0];
    const float* key_cache   = (const float*)d_in[1];
    const float* value_cache = (const float*)d_in[2];
    const int*   block_table = (const int*)d_in[3];
    const int*   positions   = (const int*)d_in[4];
    const float* Wq          = (const float*)d_in[5];
    const float* Wk          = (const float*)d_in[6];
    const float* Wv          = (const float*)d_in[7];
    const float* Wo          = (const float*)d_in[8];
    float* out = (float*)d_out;

    float* ws = (float*)d_ws;
    float* q_ws  = ws + Q_OFF;
    float* k_ws  = ws + K_OFF;
    float* v_ws  = ws + V_OFF;
    float* ao_ws = ws + AO_OFF;
    float* pml   = ws + PML_OFF;
    float* po    = ws + PO_OFF;
    float* part  = ws + PART_OFF;

    // 1) q/k/v projections: 3072 rows x 4 column-chunks
    proj_partial<<<dim3(192, CHUNKS), 256, 0, stream>>>(hidden, Wq, Wk, Wv, part, 3072);
    proj_combine<<<192, 256, 0, stream>>>(part, q_ws, k_ws, v_ws, 3072);

    // 2) flash-decode partials over the (unmodified) caches
    attn_partial<<<dim3(SPLITS, NUM_HEADS, BATCH), 256, 0, stream>>>(
        q_ws, key_cache, value_cache, block_table, positions, pml, po);

    // 3) merge splits + new-token contribution
    attn_reduce<<<BATCH * NUM_HEADS, 64, 0, stream>>>(q_ws, k_ws, v_ws, pml, po, ao_ws);

    // 4) output projection: 1024 rows x 4 column-chunks
    proj_partial<<<dim3(64, CHUNKS), 256, 0, stream>>>(ao_ws, Wo, Wo, Wo, part, 1024);
    proj_combine<<<64, 256, 0, stream>>>(part, out, out, out, 1024);
}

// Round 3
// 94.276 us; speedup vs baseline: 1.7331x; 1.2604x over previous
//
#include <hip/hip_runtime.h>
#include <math.h>

#define BATCH 16
#define NUM_HEADS 16
#define HEAD_DIM 64
#define HIDDEN 1024
#define BLOCK_SIZE 16
#define MAX_CTX 4096
#define BLOCKS_PER_SEQ 256
#define SPLITS 8
#define CHUNKS 4
#define CHUNK_F4 64    // (HIDDEN/CHUNKS)/4

// workspace layout in floats
#define Q_OFF   0
#define K_OFF   16384
#define V_OFF   32768
#define AO_OFF  49152
#define PML_OFF 65536              // BATCH*NUM_HEADS*SPLITS*2 = 4096
#define PO_OFF  69632              // BATCH*NUM_HEADS*SPLITS*64 = 131072
#define PART_OFF 200704            // CHUNKS*3072*16 = 196608

#define LOG2E 1.4426950408889634f

// Split-K GEMV partial: rows 0..1023 -> W0, 1024..2047 -> W1, 2048..3071 -> W2.
__global__ void proj_partial(const float* __restrict__ X,
                             const float* __restrict__ W0,
                             const float* __restrict__ W1,
                             const float* __restrict__ W2,
                             float* __restrict__ part, int NR) {
    const int tid = threadIdx.x;
    const int b = tid & 15;
    const int r = tid >> 4;                  // 0..15
    const int row = blockIdx.x * 16 + r;
    const int c = blockIdx.y;
    const int m = row >> 10;
    const int row_in = row & 1023;
    const float* W = (m == 0) ? W0 : (m == 1) ? W1 : W2;

    const float4* wrow = (const float4*)(W + (size_t)row_in * HIDDEN) + c * CHUNK_F4;
    const float4* xrow = (const float4*)(X + (size_t)b * HIDDEN) + c * CHUNK_F4;
    float acc = 0.f;
#pragma unroll 16
    for (int i = 0; i < CHUNK_F4; ++i) {
        float4 w4 = wrow[i];
        float4 x4 = xrow[i];
        acc += w4.x * x4.x + w4.y * x4.y + w4.z * x4.z + w4.w * x4.w;
    }
    part[((size_t)c * NR + row) * 16 + b] = acc;
}

__global__ void proj_combine(const float* __restrict__ part,
                             float* __restrict__ out0,
                             float* __restrict__ out1,
                             float* __restrict__ out2, int NR) {
    const int idx = blockIdx.x * 256 + threadIdx.x;  // row*16 + b
    const int row = idx >> 4;
    const int b = idx & 15;
    float s = 0.f;
#pragma unroll
    for (int c = 0; c < CHUNKS; ++c) s += part[((size_t)c * NR + row) * 16 + b];
    const int m = row >> 10;
    const int row_in = row & 1023;
    float* out = (m == 0) ? out0 : (m == 1) ? out1 : out2;
    out[(size_t)b * HIDDEN + row_in] = s;
}

// issue 8 x 16B loads for 64-token iteration IT (this wave's 16-token page)
#define LOAD_KV(IT, K0, K1, K2, K3, V0, V1, V2, V3)                              \
    do {                                                                          \
        const int blk_ = bt_lds[(IT) * 4 + w];                                    \
        const size_t base_ = ((size_t)blk_ * BLOCK_SIZE + g) * 1024 + hoff;       \
        const float* kp_ = key_cache + base_;                                     \
        const float* vp_ = value_cache + base_;                                   \
        K0 = *(const float4*)(kp_);                                               \
        K1 = *(const float4*)(kp_ + 4096);                                        \
        K2 = *(const float4*)(kp_ + 8192);                                        \
        K3 = *(const float4*)(kp_ + 12288);                                       \
        V0 = *(const float4*)(vp_);                                               \
        V1 = *(const float4*)(vp_ + 4096);                                        \
        V2 = *(const float4*)(vp_ + 8192);                                        \
        V3 = *(const float4*)(vp_ + 12288);                                       \
    } while (0)

#define COMPUTE(IT, K0, K1, K2, K3, V0, V1, V2, V3)                               \
    do {                                                                          \
        float d0_ = K0.x * q4.x + K0.y * q4.y + K0.z * q4.z + K0.w * q4.w;        \
        float d1_ = K1.x * q4.x + K1.y * q4.y + K1.z * q4.z + K1.w * q4.w;        \
        float d2_ = K2.x * q4.x + K2.y * q4.y + K2.z * q4.z + K2.w * q4.w;        \
        float d3_ = K3.x * q4.x + K3.y * q4.y + K3.z * q4.z + K3.w * q4.w;        \
        d0_ += __shfl_xor(d0_, 1); d1_ += __shfl_xor(d1_, 1);                     \
        d2_ += __shfl_xor(d2_, 1); d3_ += __shfl_xor(d3_, 1);                     \
        d0_ += __shfl_xor(d0_, 2); d1_ += __shfl_xor(d1_, 2);                     \
        d2_ += __shfl_xor(d2_, 2); d3_ += __shfl_xor(d3_, 2);                     \
        d0_ += __shfl_xor(d0_, 4); d1_ += __shfl_xor(d1_, 4);                     \
        d2_ += __shfl_xor(d2_, 4); d3_ += __shfl_xor(d3_, 4);                     \
        d0_ += __shfl_xor(d0_, 8); d1_ += __shfl_xor(d1_, 8);                     \
        d2_ += __shfl_xor(d2_, 8); d3_ += __shfl_xor(d3_, 8);                     \
        const int tb_ = t0 + (IT) * 64 + w * 16 + g;                              \
        if (tb_ + 0  >= t1) d0_ = -INFINITY;                                      \
        if (tb_ + 4  >= t1) d1_ = -INFINITY;                                      \
        if (tb_ + 8  >= t1) d2_ = -INFINITY;                                      \
        if (tb_ + 12 >= t1) d3_ = -INFINITY;                                      \
        const float mx_ = fmaxf(fmaxf(d0_, d1_), fmaxf(d2_, d3_));                \
        const float m_new_ = fmaxf(m, mx_);                                       \
        const float corr_ = exp2f(m - m_new_);                                    \
        const float p0_ = exp2f(d0_ - m_new_);                                    \
        const float p1_ = exp2f(d1_ - m_new_);                                    \
        const float p2_ = exp2f(d2_ - m_new_);                                    \
        const float p3_ = exp2f(d3_ - m_new_);                                    \
        l = l * corr_ + ((p0_ + p1_) + (p2_ + p3_));                              \
        o4.x = o4.x * corr_ + p0_ * V0.x + p1_ * V1.x + p2_ * V2.x + p3_ * V3.x;  \
        o4.y = o4.y * corr_ + p0_ * V0.y + p1_ * V1.y + p2_ * V2.y + p3_ * V3.y;  \
        o4.z = o4.z * corr_ + p0_ * V0.z + p1_ * V1.z + p2_ * V2.z + p3_ * V3.z;  \
        o4.w = o4.w * corr_ + p0_ * V0.w + p1_ * V1.w + p2_ * V2.w + p3_ * V3.w;  \
        m = m_new_;                                                               \
    } while (0)

// Flash-decode partial: grid (SPLITS, NUM_HEADS, BATCH), 256 threads.
// Balanced splits: split s covers [s*chunk, min((s+1)*chunk, pos)) with
// chunk = ceil(pos / (SPLITS*64)) * 64 -- every block gets ~pos/8 tokens.
// Ping-pong double-buffered K/V loads (next iter issued before current compute).
__global__ void attn_partial(const float* __restrict__ q_ws,
                             const float* __restrict__ key_cache,
                             const float* __restrict__ value_cache,
                             const int* __restrict__ block_table,
                             const int* __restrict__ positions,
                             float* __restrict__ part_ml,
                             float* __restrict__ part_o) {
    const int s = blockIdx.x;
    const int h = blockIdx.y;
    const int b = blockIdx.z;
    const int tid = threadIdx.x;          // 0..255
    const int lane = tid & 63;
    const int w = tid >> 6;               // wave 0..3
    const int g = lane >> 4;              // group-in-wave 0..3
    const int sub = lane & 15;            // 0..15
    const int gid = w * 4 + g;            // 0..15

    __shared__ int bt_lds[32];
    __shared__ float gm[16];
    __shared__ float gl[16];
    __shared__ float go[16][64];

    const int pos = positions[b];
    const int chunk = ((pos + SPLITS * 64 - 1) / (SPLITS * 64)) * 64;  // mult of 64
    const int t0 = s * chunk;
    const int t1 = min(t0 + chunk, pos);
    const int nvalid = t1 - t0;
    const int niter = (nvalid + 63) >> 6;

    // q load is independent of LDS -- issue before the barrier
    float4 q4 = ((const float4*)(q_ws + (size_t)b * HIDDEN + h * HEAD_DIM))[sub];

    // always stage 32 entries; t0>>4 <= 224 so index <= 255: always in-bounds,
    // and every staged entry is a valid cache block (safe prefetch targets).
    if (tid < 32) {
        bt_lds[tid] = block_table[b * BLOCKS_PER_SEQ + (t0 >> 4) + tid];
    }
    __syncthreads();

    const float qs = 0.125f * LOG2E;   // 1/sqrt(64) * log2(e)
    q4.x *= qs; q4.y *= qs; q4.z *= qs; q4.w *= qs;
    const int hoff = h * HEAD_DIM + sub * 4;

    float m = -1e30f;
    float l = 0.f;
    float4 o4 = {0.f, 0.f, 0.f, 0.f};

    float4 kA0, kA1, kA2, kA3, vA0, vA1, vA2, vA3;
    float4 kB0, kB1, kB2, kB3, vB0, vB1, vB2, vB3;

    if (niter > 0) {
        LOAD_KV(0, kA0, kA1, kA2, kA3, vA0, vA1, vA2, vA3);
        int it = 0;
        while (true) {
            if (it + 1 < niter) LOAD_KV(it + 1, kB0, kB1, kB2, kB3, vB0, vB1, vB2, vB3);
            COMPUTE(it, kA0, kA1, kA2, kA3, vA0, vA1, vA2, vA3);
            ++it;
            if (it >= niter) break;
            if (it + 1 < niter) LOAD_KV(it + 1, kA0, kA1, kA2, kA3, vA0, vA1, vA2, vA3);
            COMPUTE(it, kB0, kB1, kB2, kB3, vB0, vB1, vB2, vB3);
            ++it;
            if (it >= niter) break;
        }
    }

    go[gid][sub * 4 + 0] = o4.x;
    go[gid][sub * 4 + 1] = o4.y;
    go[gid][sub * 4 + 2] = o4.z;
    go[gid][sub * 4 + 3] = o4.w;
    if (sub == 0) { gm[gid] = m; gl[gid] = l; }
    __syncthreads();

    if (tid < 64) {
        const int d = tid;
        float M = -1e30f;
#pragma unroll
        for (int gi = 0; gi < 16; ++gi) M = fmaxf(M, gm[gi]);
        float L = 0.f, O = 0.f;
#pragma unroll
        for (int gi = 0; gi < 16; ++gi) {
            const float sc = exp2f(gm[gi] - M);   // log2-domain maxes
            L += gl[gi] * sc;
            O += go[gi][d] * sc;
        }
        const int pidx = (b * NUM_HEADS + h) * SPLITS + s;
        part_o[(size_t)pidx * 64 + d] = O;
        if (d == 0) {
            part_ml[pidx * 2 + 0] = M;   // log2 domain
            part_ml[pidx * 2 + 1] = L;
        }
    }
}

// Merge split partials + the new-token (tok == pos) term. grid = B*H, 64 thr.
__global__ void attn_reduce(const float* __restrict__ q_ws,
                            const float* __restrict__ k_ws,
                            const float* __restrict__ v_ws,
                            const float* __restrict__ part_ml,
                            const float* __restrict__ part_o,
                            float* __restrict__ attn_out) {
    const int bh = blockIdx.x;          // b*16 + h
    const int b = bh >> 4;
    const int h = bh & 15;
    const int d = threadIdx.x;          // 0..63

    const size_t vecoff = (size_t)b * HIDDEN + h * HEAD_DIM + d;
    const float qd = q_ws[vecoff];
    const float kd = k_ws[vecoff];
    float pr = qd * kd;
    pr += __shfl_xor(pr, 1);
    pr += __shfl_xor(pr, 2);
    pr += __shfl_xor(pr, 4);
    pr += __shfl_xor(pr, 8);
    pr += __shfl_xor(pr, 16);
    pr += __shfl_xor(pr, 32);
    const float s_new = pr * (0.125f * LOG2E);   // log2 domain

    float M = s_new;
#pragma unroll
    for (int sp = 0; sp < SPLITS; ++sp)
        M = fmaxf(M, part_ml[(bh * SPLITS + sp) * 2]);

    float L = exp2f(s_new - M);
    float O = L * v_ws[vecoff];
#pragma unroll
    for (int sp = 0; sp < SPLITS; ++sp) {
        const float mg = part_ml[(bh * SPLITS + sp) * 2 + 0];
        const float lg = part_ml[(bh * SPLITS + sp) * 2 + 1];
        const float sc = exp2f(mg - M);
        L += lg * sc;
        O += part_o[(size_t)(bh * SPLITS + sp) * 64 + d] * sc;
    }
    attn_out[vecoff] = O / L;
}

extern "C" void kernel_launch(void* const* d_in, const int* in_sizes, int n_in,
                              void* d_out, int out_size, void* d_ws, size_t ws_size,
                              hipStream_t stream) {
    const float* hidden      = (const float*)d_in[0];
    const float* key_cache   = (const float*)d_in[1];
    const float* value_cache = (const float*)d_in[2];
    const int*   block_table = (const int*)d_in[3];
    const int*   positions   = (const int*)d_in[4];
    const float* Wq          = (const float*)d_in[5];
    const float* Wk          = (const float*)d_in[6];
    const float* Wv          = (const float*)d_in[7];
    const float* Wo          = (const float*)d_in[8];
    float* out = (float*)d_out;

    float* ws = (float*)d_ws;
    float* q_ws  = ws + Q_OFF;
    float* k_ws  = ws + K_OFF;
    float* v_ws  = ws + V_OFF;
    float* ao_ws = ws + AO_OFF;
    float* pml   = ws + PML_OFF;
    float* po    = ws + PO_OFF;
    float* part  = ws + PART_OFF;

    // 1) q/k/v projections: 3072 rows x 4 column-chunks
    proj_partial<<<dim3(192, CHUNKS), 256, 0, stream>>>(hidden, Wq, Wk, Wv, part, 3072);
    proj_combine<<<192, 256, 0, stream>>>(part, q_ws, k_ws, v_ws, 3072);

    // 2) flash-decode partials over the (unmodified) caches
    attn_partial<<<dim3(SPLITS, NUM_HEADS, BATCH), 256, 0, stream>>>(
        q_ws, key_cache, value_cache, block_table, positions, pml, po);

    // 3) merge splits + new-token contribution
    attn_reduce<<<BATCH * NUM_HEADS, 64, 0, stream>>>(q_ws, k_ws, v_ws, pml, po, ao_ws);

    // 4) output projection: 1024 rows x 4 column-chunks
    proj_partial<<<dim3(64, CHUNKS), 256, 0, stream>>>(ao_ws, Wo, Wo, Wo, part, 1024);
    proj_combine<<<64, 256, 0, stream>>>(part, out, out, out, 1024);
}